// Round 17
// baseline (135.468 us; speedup 1.0000x reference)
//
#include <hip/hip_runtime.h>
#include <cstdint>
#include <cstddef>

// Problem constants
#define K_ 512
#define T_ 32768
#define CHUNKS 4096
#define LSTEP 8            // T_/CHUNKS
#define NGRP 256           // CHUNKS/16 (16 chunk-columns per WG)

// workspace layout (bytes) -- total ~25.8 MB (<= 26.2 MB proven)
#define OFF_E8    0ul        // 512*512 fp8 row-major
#define OFF_ET8   262144ul   // transposed fp8
#define OFF_U     524288ul   // 4096 x 512 bf16 = 4 MB
#define OFF_Z     4718592ul  // 4096 x 512 bf16 = 4 MB
#define OFF_GPART 8912896ul  // 32 f32
#define OFF_ALED  8913024ul  // 4096 int
#define OFF_BLED  8929408ul  // 4096 int
#define OFF_SSUM  8945792ul  // 4096 f32
#define OFF_PARTS 8962176ul  // 4096 double (end 8994560)
#define OFF_EXPT  8994560ul  // expT[t][k] fp8: 32768*512 = 16 MB (end 25771904)

#define FP8MAX 440.f

typedef float f32x4 __attribute__((ext_vector_type(4)));
typedef int i32x8 __attribute__((ext_vector_type(8)));

static __device__ __forceinline__ unsigned short f2bf(float x) {
  unsigned u = __float_as_uint(x);
  u += 0x7fffu + ((u >> 16) & 1u);
  return (unsigned short)(u >> 16);
}
static __device__ __forceinline__ float bf2f(unsigned short h) {
  return __uint_as_float(((unsigned)h) << 16);
}

// 32B LDS fragment via 4x ds_read_b64 (conflict-free at stride 520; r4-r16 validated)
static __device__ __forceinline__ i32x8 lds_ld32(const uint8_t* p) {
  long long a = *(const long long*)p;
  long long b = *(const long long*)(p + 8);
  long long c = *(const long long*)(p + 16);
  long long d = *(const long long*)(p + 24);
  i32x8 r;
  r[0] = (int)a; r[1] = (int)(a >> 32);
  r[2] = (int)b; r[3] = (int)(b >> 32);
  r[4] = (int)c; r[5] = (int)(c >> 32);
  r[6] = (int)d; r[7] = (int)(d >> 32);
  return r;
}

// ---------------- prep: E8 = fp8(exp(tr)) row-major AND transposed ----------------
__global__ __launch_bounds__(512) void prep_k(const float* __restrict__ tr,
                                              uint8_t* __restrict__ E8,
                                              uint8_t* __restrict__ ET8) {
  int i = blockIdx.x;       // row
  int j = threadIdx.x;      // col
  float e = fminf(__expf(tr[i * 512 + j]), FP8MAX);
  int w = __builtin_amdgcn_cvt_pk_fp8_f32(e, e, 0, false);
  uint8_t b = (uint8_t)(w & 0xff);
  E8[i * 512 + j] = b;
  ET8[(size_t)j * 512 + i] = b;
}

// ---------------- texp: expT[t][k] = fp8(exp(obs[k][t])), 64x64 LDS tile ----------------
__global__ __launch_bounds__(256) void texp_k(const float* __restrict__ obs,
                                              uint8_t* __restrict__ expT) {
  __shared__ uint8_t tile[64][68];     // t-major in tile, padded (4B-aligned rows)
  const int t0 = (blockIdx.x & 511) * 64;   // T/64 = 512
  const int k0 = (blockIdx.x >> 9) * 64;    // K/64 = 8
  const int tx = threadIdx.x & 63;          // t offset (coalesced read dim)
  const int ky = threadIdx.x >> 6;          // 0..3
#pragma unroll
  for (int q = 0; q < 16; ++q) {
    int k = ky * 16 + q;                    // 0..63
    float v = obs[(size_t)(k0 + k) * T_ + t0 + tx];
    float e = fminf(__expf(v), FP8MAX);
    int w = __builtin_amdgcn_cvt_pk_fp8_f32(e, e, 0, false);
    tile[tx][k] = (uint8_t)(w & 0xff);
  }
  __syncthreads();
  // write out: thread -> (t-row ty, 16-byte k segment)
  const int ty = threadIdx.x >> 2;          // 0..63
  const int kq = (threadIdx.x & 3) * 16;    // 0,16,32,48
  const uint8_t* src = &tile[ty][kq];
  uint4 o;
  o.x = *(const unsigned*)(src + 0);
  o.y = *(const unsigned*)(src + 4);
  o.z = *(const unsigned*)(src + 8);
  o.w = *(const unsigned*)(src + 12);
  *(uint4*)(expT + (size_t)(t0 + ty) * 512 + k0 + kq) = o;
}

// ---------------- gold score (exact f32, deterministic, 32 partials) ----------------
__global__ __launch_bounds__(1024) void gold_k(const float* __restrict__ obs,
                                               const int* __restrict__ tags,
                                               const float* __restrict__ tr,
                                               float* __restrict__ gpart) {
  __shared__ float red[1024];
  int i = blockIdx.x * 1024 + threadIdx.x;
  float s = 0.f;
  if (i < T_ - 1) {
    int cur = tags[i], nxt = tags[i + 1];
    s = tr[nxt * K_ + cur] + obs[(size_t)nxt * T_ + i];
  }
  red[threadIdx.x] = s;
  __syncthreads();
  for (int h = 512; h > 0; h >>= 1) {
    if ((int)threadIdx.x < h) red[threadIdx.x] += red[threadIdx.x + h];
    __syncthreads();
  }
  if (threadIdx.x == 0) gpart[blockIdx.x] = red[0];
}

// ---------------- uv: 16 chunk recurrences per WG via MFMA ----------------
// r16 structure (validated absmax 0.0 at LSTEP=16), now LSTEP=8 / 512 WGs so 2 WGs
// co-reside per CU (launch_bounds (512,4); VGPR 100 < 128 cap): one WG's MFMAs
// fill the other's barrier/latency stalls -- r16 was serial-latency-bound at
// 1 WG/CU (6450 cyc/step vs 1100 cyc MFMA). Final u/z stored bf16 (ws budget).
__global__ __launch_bounds__(512, 4)
void uv_k(const uint8_t* __restrict__ E8, const uint8_t* __restrict__ ET8,
          const uint8_t* __restrict__ expT,
          unsigned short* __restrict__ U, unsigned short* __restrict__ Z,
          int* __restrict__ Aled, int* __restrict__ Bled,
          float* __restrict__ Ssum) {
  __shared__ __align__(16) uint8_t Vb[2][16 * 520];   // 16640 B
  __shared__ float cred[8][16];                       // per-wave col max / col sum

  const int tid = threadIdx.x;
  const int wv = tid >> 6;
  const int lane = tid & 63;
  const int l15 = lane & 15;
  const int g = lane >> 4;
  const int dir = blockIdx.x & 1;
  const int grp = blockIdx.x >> 1;
  const int tbase = (grp * 16 + l15) * LSTEP;   // t0 of this lane's column

  // E (or E^T) fragments: lane holds A[row=64wv+16rt+l15][k=128kt+32g..+31]
  const uint8_t* M = dir ? ET8 : E8;
  i32x8 ef[4][4];
#pragma unroll
  for (int rt = 0; rt < 4; ++rt)
#pragma unroll
    for (int kt = 0; kt < 4; ++kt)
      ef[rt][kt] = *(const i32x8*)(M +
          ((64 * wv + 16 * rt + l15) * 512 + 128 * kt + 32 * g));

  // init V[0]
  if (dir == 0) {
    for (int i = tid; i < 16 * 520 / 4; i += 512)
      ((int*)Vb[0])[i] = 0x38383838;               // fp8 1.0 everywhere (pad unused)
  } else {
#pragma unroll
    for (int c = 0; c < 16; ++c)
      Vb[0][c * 520 + tid] =
          expT[(size_t)((grp * 16 + c) * LSTEP + (LSTEP - 1)) * 512 + tid];
  }
  __syncthreads();

  int led = 0;                                     // ledger for column l15
  const f32x4 z4 = (f32x4){0.f, 0.f, 0.f, 0.f};

  f32x4 acc[4];

#pragma unroll 1
  for (int s = 0; s < LSTEP; ++s) {
    const uint8_t* Vr = Vb[s & 1];
    uint8_t* Vw = Vb[(s & 1) ^ 1];

    // issue this step's exp-factor loads FIRST (latency hides under MFMA chain)
    const int te = dir ? (tbase + LSTEP - 2 - s) : (tbase + s);
    const bool doexp = (dir == 0) || (s < LSTEP - 1);
    unsigned ew[4];
    if (doexp) {
      const uint8_t* ep = expT + (size_t)te * 512 + 64 * wv + 4 * g;
#pragma unroll
      for (int rt = 0; rt < 4; ++rt) ew[rt] = *(const unsigned*)(ep + 16 * rt);
    }

    // MFMA phase: acc[rt] = sum_kt E[rt][kt] x V[kt][l15-col]
    {
      const uint8_t* pb = Vr + l15 * 520 + 32 * g;
      i32x8 b = lds_ld32(pb);
#pragma unroll
      for (int rt = 0; rt < 4; ++rt)
        acc[rt] = __builtin_amdgcn_mfma_scale_f32_16x16x128_f8f6f4(
            ef[rt][0], b, z4, 0, 0, 0, 0x7f7f7f7f, 0, 0x7f7f7f7f);
#pragma unroll
      for (int kt = 1; kt < 4; ++kt) {
        b = lds_ld32(pb + 128 * kt);
#pragma unroll
        for (int rt = 0; rt < 4; ++rt)
          acc[rt] = __builtin_amdgcn_mfma_scale_f32_16x16x128_f8f6f4(
              ef[rt][kt], b, acc[rt], 0, 0, 0, 0x7f7f7f7f, 0, 0x7f7f7f7f);
      }
    }

    // epilogue: scale by fp8 exp factor (except dir1 last step); literal selects
    float vmax = 0.f;
#pragma unroll
    for (int rt = 0; rt < 4; ++rt) {
      float v0 = acc[rt][0], v1 = acc[rt][1], v2 = acc[rt][2], v3 = acc[rt][3];
      if (doexp) {
        int w = (int)ew[rt];
        v0 *= __builtin_amdgcn_cvt_f32_fp8(w, 0);
        v1 *= __builtin_amdgcn_cvt_f32_fp8(w, 1);
        v2 *= __builtin_amdgcn_cvt_f32_fp8(w, 2);
        v3 *= __builtin_amdgcn_cvt_f32_fp8(w, 3);
      }
      acc[rt][0] = v0; acc[rt][1] = v1; acc[rt][2] = v2; acc[rt][3] = v3;
      vmax = fmaxf(vmax, fmaxf(fmaxf(v0, v1), fmaxf(v2, v3)));
    }

    if (s == LSTEP - 1) break;

    // exact per-column renorm: col max over g (shfl) then over waves (LDS)
    vmax = fmaxf(vmax, __shfl_xor(vmax, 16, 64));
    vmax = fmaxf(vmax, __shfl_xor(vmax, 32, 64));
    if (lane < 16) cred[wv][lane] = vmax;
    __syncthreads();
    float cm = cred[0][l15];
#pragma unroll
    for (int q = 1; q < 8; ++q) cm = fmaxf(cm, cred[q][l15]);
    int e = (int)((__float_as_uint(cm) >> 23) & 255) - 127;
    e = min(max(e, -120), 120);
    int sg = e - 7;                       // stored col max in [128,256)
    led += sg;
    float sc = __uint_as_float((unsigned)(127 - sg) << 23);

#pragma unroll
    for (int rt = 0; rt < 4; ++rt) {
      float v0 = acc[rt][0] * sc, v1 = acc[rt][1] * sc;
      float v2 = acc[rt][2] * sc, v3 = acc[rt][3] * sc;
      int w32 = __builtin_amdgcn_cvt_pk_fp8_f32(v0, v1, 0, false);
      w32 = __builtin_amdgcn_cvt_pk_fp8_f32(v2, v3, w32, true);
      *(int*)(Vw + l15 * 520 + 64 * wv + 16 * rt + 4 * g) = w32;
    }
    __syncthreads();
  }

  // final store: bf16 vectors (chunk = grp*16 + l15), ledgers, Ssum (dir 0; f32 acc)
  unsigned short* dst =
      (dir ? Z : U) + (size_t)(grp * 16 + l15) * 512 + 64 * wv + 4 * g;
#pragma unroll
  for (int rt = 0; rt < 4; ++rt) {
    unsigned o0 = (unsigned)f2bf(acc[rt][0]) | ((unsigned)f2bf(acc[rt][1]) << 16);
    unsigned o1 = (unsigned)f2bf(acc[rt][2]) | ((unsigned)f2bf(acc[rt][3]) << 16);
    uint2 o; o.x = o0; o.y = o1;
    *(uint2*)(dst + 16 * rt) = o;
  }

  if (dir == 0) {
    float ssum = 0.f;
#pragma unroll
    for (int rt = 0; rt < 4; ++rt)
#pragma unroll
      for (int j = 0; j < 4; ++j) ssum += acc[rt][j];
    ssum += __shfl_xor(ssum, 16, 64);
    ssum += __shfl_xor(ssum, 32, 64);
    if (lane < 16) cred[wv][lane] = ssum;
    __syncthreads();
    if (wv == 0 && lane < 16) {
      float t = 0.f;
#pragma unroll
      for (int q = 0; q < 8; ++q) t += cred[q][lane];
      Ssum[grp * 16 + lane] = t;
      Aled[grp * 16 + lane] = led;
    }
  } else {
    if (wv == 0 && lane < 16) Bled[grp * 16 + lane] = led;
  }
}

// ---------------- combine: parts[cc] = ln(z_cc . u_{cc-1}) + ledgers - ln(s_cc) ----------------
__global__ __launch_bounds__(64) void combine_k(const unsigned short* __restrict__ U,
                                                const unsigned short* __restrict__ Z,
                                                const int* __restrict__ Aled,
                                                const int* __restrict__ Bled,
                                                const float* __restrict__ Ssum,
                                                double* __restrict__ parts) {
  int cc = blockIdx.x + 1;           // 1..CHUNKS-1
  int lane = threadIdx.x;
  float p = 0.f;
  for (int r = lane; r < 512; r += 64)
    p += bf2f(Z[(size_t)cc * 512 + r]) * bf2f(U[(size_t)(cc - 1) * 512 + r]);
#pragma unroll
  for (int off = 1; off < 64; off <<= 1) p += __shfl_xor(p, off, 64);
  if (lane == 0) {
    const double LN2 = 0.69314718055994530942;
    double term = log((double)p) + LN2 * (double)(Aled[cc - 1] + Bled[cc]);
    if (cc <= CHUNKS - 2)
      term -= log((double)Ssum[cc]) + LN2 * (double)Aled[cc];
    parts[cc] = term;
  }
}

// ---------------- final: out = sum(parts) - gold ----------------
__global__ __launch_bounds__(256) void final2_k(const double* __restrict__ parts,
                                                const float* __restrict__ gpart,
                                                float* __restrict__ outp) {
  __shared__ double red[256];
  double s = 0.0;
  for (int i = 1 + (int)threadIdx.x; i < CHUNKS; i += 256) s += parts[i];
  red[threadIdx.x] = s;
  __syncthreads();
  for (int h = 128; h > 0; h >>= 1) {
    if ((int)threadIdx.x < h) red[threadIdx.x] += red[threadIdx.x + h];
    __syncthreads();
  }
  if (threadIdx.x == 0) {
    double g = 0.0;
    for (int q = 0; q < 32; ++q) g += (double)gpart[q];
    outp[0] = (float)(red[0] - g);
  }
}

extern "C" void kernel_launch(void* const* d_in, const int* in_sizes, int n_in,
                              void* d_out, int out_size, void* d_ws, size_t ws_size,
                              hipStream_t stream) {
  const float* obs = (const float*)d_in[0];   // (K, T) f32
  const int* tags = (const int*)d_in[1];      // (T,) i32
  const float* tr = (const float*)d_in[2];    // (K, K) f32
  float* out = (float*)d_out;

  uint8_t* ws = (uint8_t*)d_ws;
  uint8_t* E8 = ws + OFF_E8;
  uint8_t* ET8 = ws + OFF_ET8;
  unsigned short* U = (unsigned short*)(ws + OFF_U);
  unsigned short* Z = (unsigned short*)(ws + OFF_Z);
  float* gpart = (float*)(ws + OFF_GPART);
  int* Aled = (int*)(ws + OFF_ALED);
  int* Bled = (int*)(ws + OFF_BLED);
  float* Ssum = (float*)(ws + OFF_SSUM);
  double* parts = (double*)(ws + OFF_PARTS);
  uint8_t* expT = ws + OFF_EXPT;

  hipLaunchKernelGGL(prep_k, dim3(512), dim3(512), 0, stream, tr, E8, ET8);
  hipLaunchKernelGGL(texp_k, dim3(512 * 8), dim3(256), 0, stream, obs, expT);
  hipLaunchKernelGGL(gold_k, dim3(32), dim3(1024), 0, stream, obs, tags, tr, gpart);
  hipLaunchKernelGGL(uv_k, dim3(NGRP * 2), dim3(512), 0, stream,
                     E8, ET8, expT, U, Z, Aled, Bled, Ssum);
  hipLaunchKernelGGL(combine_k, dim3(CHUNKS - 1), dim3(64), 0, stream,
                     U, Z, Aled, Bled, Ssum, parts);
  hipLaunchKernelGGL(final2_k, dim3(1), dim3(256), 0, stream, parts, gpart, out);
}

// Round 18
// 84.919 us; speedup vs baseline: 1.5953x; 1.5953x over previous
//
#include <hip/hip_runtime.h>
#include <cstdint>
#include <cstddef>

// Problem constants
#define K_ 512
#define T_ 32768
#define CHUNKS 4096
#define LSTEP 8            // T_/CHUNKS
#define NGRP 128           // CHUNKS/32 (32 chunk-columns per WG: 2 groups of 16)

// workspace layout (bytes) -- total ~25.8 MB
#define OFF_E8    0ul        // 512*512 fp8 row-major
#define OFF_ET8   262144ul   // transposed fp8
#define OFF_U     524288ul   // 4096 x 512 bf16 = 4 MB
#define OFF_Z     4718592ul  // 4096 x 512 bf16 = 4 MB
#define OFF_GPART 8912896ul  // 32 f32
#define OFF_ALED  8913024ul  // 4096 int
#define OFF_BLED  8929408ul  // 4096 int
#define OFF_SSUM  8945792ul  // 4096 f32
#define OFF_PARTS 8962176ul  // 4096 double (end 8994560)
#define OFF_EXPT  8994560ul  // expT[t][k] fp8: 32768*512 = 16 MB (end 25771904)

#define FP8MAX 440.f

typedef float f32x4 __attribute__((ext_vector_type(4)));
typedef int i32x8 __attribute__((ext_vector_type(8)));

static __device__ __forceinline__ unsigned short f2bf(float x) {
  unsigned u = __float_as_uint(x);
  u += 0x7fffu + ((u >> 16) & 1u);
  return (unsigned short)(u >> 16);
}
static __device__ __forceinline__ float bf2f(unsigned short h) {
  return __uint_as_float(((unsigned)h) << 16);
}

// 32B LDS fragment via 4x ds_read_b64 (conflict-free at stride 520; r4-r16 validated)
static __device__ __forceinline__ i32x8 lds_ld32(const uint8_t* p) {
  long long a = *(const long long*)p;
  long long b = *(const long long*)(p + 8);
  long long c = *(const long long*)(p + 16);
  long long d = *(const long long*)(p + 24);
  i32x8 r;
  r[0] = (int)a; r[1] = (int)(a >> 32);
  r[2] = (int)b; r[3] = (int)(b >> 32);
  r[4] = (int)c; r[5] = (int)(c >> 32);
  r[6] = (int)d; r[7] = (int)(d >> 32);
  return r;
}

// ---------------- prep: E8 = fp8(exp(tr)) row-major AND transposed ----------------
__global__ __launch_bounds__(512) void prep_k(const float* __restrict__ tr,
                                              uint8_t* __restrict__ E8,
                                              uint8_t* __restrict__ ET8) {
  int i = blockIdx.x;       // row
  int j = threadIdx.x;      // col
  float e = fminf(__expf(tr[i * 512 + j]), FP8MAX);
  int w = __builtin_amdgcn_cvt_pk_fp8_f32(e, e, 0, false);
  uint8_t b = (uint8_t)(w & 0xff);
  E8[i * 512 + j] = b;
  ET8[(size_t)j * 512 + i] = b;
}

// ---------------- texp: expT[t][k] = fp8(exp(obs[k][t])), 64x64 LDS tile ----------------
__global__ __launch_bounds__(256) void texp_k(const float* __restrict__ obs,
                                              uint8_t* __restrict__ expT) {
  __shared__ uint8_t tile[64][68];
  const int t0 = (blockIdx.x & 511) * 64;
  const int k0 = (blockIdx.x >> 9) * 64;
  const int tx = threadIdx.x & 63;
  const int ky = threadIdx.x >> 6;
#pragma unroll
  for (int q = 0; q < 16; ++q) {
    int k = ky * 16 + q;
    float v = obs[(size_t)(k0 + k) * T_ + t0 + tx];
    float e = fminf(__expf(v), FP8MAX);
    int w = __builtin_amdgcn_cvt_pk_fp8_f32(e, e, 0, false);
    tile[tx][k] = (uint8_t)(w & 0xff);
  }
  __syncthreads();
  const int ty = threadIdx.x >> 2;
  const int kq = (threadIdx.x & 3) * 16;
  const uint8_t* src = &tile[ty][kq];
  uint4 o;
  o.x = *(const unsigned*)(src + 0);
  o.y = *(const unsigned*)(src + 4);
  o.z = *(const unsigned*)(src + 8);
  o.w = *(const unsigned*)(src + 12);
  *(uint4*)(expT + (size_t)(t0 + ty) * 512 + k0 + kq) = o;
}

// ---------------- gold score (exact f32, deterministic, 32 partials) ----------------
__global__ __launch_bounds__(1024) void gold_k(const float* __restrict__ obs,
                                               const int* __restrict__ tags,
                                               const float* __restrict__ tr,
                                               float* __restrict__ gpart) {
  __shared__ float red[1024];
  int i = blockIdx.x * 1024 + threadIdx.x;
  float s = 0.f;
  if (i < T_ - 1) {
    int cur = tags[i], nxt = tags[i + 1];
    s = tr[nxt * K_ + cur] + obs[(size_t)nxt * T_ + i];
  }
  red[threadIdx.x] = s;
  __syncthreads();
  for (int h = 512; h > 0; h >>= 1) {
    if ((int)threadIdx.x < h) red[threadIdx.x] += red[threadIdx.x + h];
    __syncthreads();
  }
  if (threadIdx.x == 0) gpart[blockIdx.x] = red[0];
}

// ---------------- uv: 32 chunk recurrences per WG (2 groups x 16) via MFMA ----------------
// r16 structure (validated absmax 0.0) + dual-chain ILP: groups A and B are
// independent recurrences sharing the same E fragments; their MFMA chains are
// interleaved per kt so each chain's ds_read/MFMA/exp-load latency hides under
// the other's issue (r16 was latency-bound: pipes 14%/15%, 1 WG/CU, no TLP
// possible since E-residency needs the 256-reg tier -> launch_bounds(512,2)).
// Barriers shared by both groups: 2 per step for 2x the columns.
__global__ __launch_bounds__(512, 2)
void uv_k(const uint8_t* __restrict__ E8, const uint8_t* __restrict__ ET8,
          const uint8_t* __restrict__ expT,
          unsigned short* __restrict__ U, unsigned short* __restrict__ Z,
          int* __restrict__ Aled, int* __restrict__ Bled,
          float* __restrict__ Ssum) {
  __shared__ __align__(16) uint8_t VbA[2][16 * 520];  // 16640 B
  __shared__ __align__(16) uint8_t VbB[2][16 * 520];  // 16640 B
  __shared__ float cred[8][32];                       // [wave][col(A:0-15,B:16-31)]

  const int tid = threadIdx.x;
  const int wv = tid >> 6;
  const int lane = tid & 63;
  const int l15 = lane & 15;
  const int g = lane >> 4;
  const int dir = blockIdx.x & 1;
  const int grp = blockIdx.x >> 1;
  const int chA = grp * 32 + l15;          // group-A chunk of this lane
  const int chB = grp * 32 + 16 + l15;     // group-B chunk
  const int tbA = chA * LSTEP;
  const int tbB = chB * LSTEP;

  // E (or E^T) fragments: lane holds A[row=64wv+16rt+l15][k=128kt+32g..+31]
  const uint8_t* M = dir ? ET8 : E8;
  i32x8 ef[4][4];
#pragma unroll
  for (int rt = 0; rt < 4; ++rt)
#pragma unroll
    for (int kt = 0; kt < 4; ++kt)
      ef[rt][kt] = *(const i32x8*)(M +
          ((64 * wv + 16 * rt + l15) * 512 + 128 * kt + 32 * g));

  // init V[0] for both groups
  if (dir == 0) {
    for (int i = tid; i < 16 * 520 / 4; i += 512) {
      ((int*)VbA[0])[i] = 0x38383838;      // fp8 1.0
      ((int*)VbB[0])[i] = 0x38383838;
    }
  } else {
#pragma unroll
    for (int c = 0; c < 16; ++c) {
      VbA[0][c * 520 + tid] =
          expT[(size_t)((grp * 32 + c) * LSTEP + (LSTEP - 1)) * 512 + tid];
      VbB[0][c * 520 + tid] =
          expT[(size_t)((grp * 32 + 16 + c) * LSTEP + (LSTEP - 1)) * 512 + tid];
    }
  }
  __syncthreads();

  int ledA = 0, ledB = 0;
  const f32x4 z4 = (f32x4){0.f, 0.f, 0.f, 0.f};
  f32x4 accA[4], accB[4];

#pragma unroll 1
  for (int s = 0; s < LSTEP; ++s) {
    // exp-factor loads for both groups first (latency hides under MFMA chains)
    const int teA = dir ? (tbA + LSTEP - 2 - s) : (tbA + s);
    const int teB = dir ? (tbB + LSTEP - 2 - s) : (tbB + s);
    const bool doexp = (dir == 0) || (s < LSTEP - 1);
    unsigned ewA[4], ewB[4];
    if (doexp) {
      const uint8_t* ea = expT + (size_t)teA * 512 + 64 * wv + 4 * g;
      const uint8_t* eb = expT + (size_t)teB * 512 + 64 * wv + 4 * g;
#pragma unroll
      for (int rt = 0; rt < 4; ++rt) {
        ewA[rt] = *(const unsigned*)(ea + 16 * rt);
        ewB[rt] = *(const unsigned*)(eb + 16 * rt);
      }
    }

    // dual MFMA chains, interleaved per kt (independent accumulators)
    {
      const uint8_t* pa = VbA[s & 1] + l15 * 520 + 32 * g;
      const uint8_t* pb = VbB[s & 1] + l15 * 520 + 32 * g;
#pragma unroll
      for (int kt = 0; kt < 4; ++kt) {
        i32x8 bA = lds_ld32(pa + 128 * kt);
        i32x8 bB = lds_ld32(pb + 128 * kt);
        if (kt == 0) {
#pragma unroll
          for (int rt = 0; rt < 4; ++rt) {
            accA[rt] = __builtin_amdgcn_mfma_scale_f32_16x16x128_f8f6f4(
                ef[rt][0], bA, z4, 0, 0, 0, 0x7f7f7f7f, 0, 0x7f7f7f7f);
            accB[rt] = __builtin_amdgcn_mfma_scale_f32_16x16x128_f8f6f4(
                ef[rt][0], bB, z4, 0, 0, 0, 0x7f7f7f7f, 0, 0x7f7f7f7f);
          }
        } else {
#pragma unroll
          for (int rt = 0; rt < 4; ++rt) {
            accA[rt] = __builtin_amdgcn_mfma_scale_f32_16x16x128_f8f6f4(
                ef[rt][kt], bA, accA[rt], 0, 0, 0, 0x7f7f7f7f, 0, 0x7f7f7f7f);
            accB[rt] = __builtin_amdgcn_mfma_scale_f32_16x16x128_f8f6f4(
                ef[rt][kt], bB, accB[rt], 0, 0, 0, 0x7f7f7f7f, 0, 0x7f7f7f7f);
          }
        }
      }
    }

    // epilogues: scale by fp8 exp factors (literal byte-selects)
    float vmaxA = 0.f, vmaxB = 0.f;
#pragma unroll
    for (int rt = 0; rt < 4; ++rt) {
      float a0 = accA[rt][0], a1 = accA[rt][1], a2 = accA[rt][2], a3 = accA[rt][3];
      float b0 = accB[rt][0], b1 = accB[rt][1], b2 = accB[rt][2], b3 = accB[rt][3];
      if (doexp) {
        int wa = (int)ewA[rt], wb = (int)ewB[rt];
        a0 *= __builtin_amdgcn_cvt_f32_fp8(wa, 0);
        a1 *= __builtin_amdgcn_cvt_f32_fp8(wa, 1);
        a2 *= __builtin_amdgcn_cvt_f32_fp8(wa, 2);
        a3 *= __builtin_amdgcn_cvt_f32_fp8(wa, 3);
        b0 *= __builtin_amdgcn_cvt_f32_fp8(wb, 0);
        b1 *= __builtin_amdgcn_cvt_f32_fp8(wb, 1);
        b2 *= __builtin_amdgcn_cvt_f32_fp8(wb, 2);
        b3 *= __builtin_amdgcn_cvt_f32_fp8(wb, 3);
      }
      accA[rt][0] = a0; accA[rt][1] = a1; accA[rt][2] = a2; accA[rt][3] = a3;
      accB[rt][0] = b0; accB[rt][1] = b1; accB[rt][2] = b2; accB[rt][3] = b3;
      vmaxA = fmaxf(vmaxA, fmaxf(fmaxf(a0, a1), fmaxf(a2, a3)));
      vmaxB = fmaxf(vmaxB, fmaxf(fmaxf(b0, b1), fmaxf(b2, b3)));
    }

    if (s == LSTEP - 1) break;

    // exact per-column renorm, both groups, ONE cred barrier
    vmaxA = fmaxf(vmaxA, __shfl_xor(vmaxA, 16, 64));
    vmaxA = fmaxf(vmaxA, __shfl_xor(vmaxA, 32, 64));
    vmaxB = fmaxf(vmaxB, __shfl_xor(vmaxB, 16, 64));
    vmaxB = fmaxf(vmaxB, __shfl_xor(vmaxB, 32, 64));
    if (lane < 16) {
      cred[wv][lane] = vmaxA;
      cred[wv][16 + lane] = vmaxB;
    }
    __syncthreads();
    float cmA = cred[0][l15], cmB = cred[0][16 + l15];
#pragma unroll
    for (int q = 1; q < 8; ++q) {
      cmA = fmaxf(cmA, cred[q][l15]);
      cmB = fmaxf(cmB, cred[q][16 + l15]);
    }
    int eA = (int)((__float_as_uint(cmA) >> 23) & 255) - 127;
    int eB = (int)((__float_as_uint(cmB) >> 23) & 255) - 127;
    eA = min(max(eA, -120), 120); eB = min(max(eB, -120), 120);
    int sgA = eA - 7, sgB = eB - 7;
    ledA += sgA; ledB += sgB;
    float scA = __uint_as_float((unsigned)(127 - sgA) << 23);
    float scB = __uint_as_float((unsigned)(127 - sgB) << 23);

    uint8_t* VwA = VbA[(s & 1) ^ 1];
    uint8_t* VwB = VbB[(s & 1) ^ 1];
#pragma unroll
    for (int rt = 0; rt < 4; ++rt) {
      float a0 = accA[rt][0] * scA, a1 = accA[rt][1] * scA;
      float a2 = accA[rt][2] * scA, a3 = accA[rt][3] * scA;
      int wa = __builtin_amdgcn_cvt_pk_fp8_f32(a0, a1, 0, false);
      wa = __builtin_amdgcn_cvt_pk_fp8_f32(a2, a3, wa, true);
      *(int*)(VwA + l15 * 520 + 64 * wv + 16 * rt + 4 * g) = wa;
      float b0 = accB[rt][0] * scB, b1 = accB[rt][1] * scB;
      float b2 = accB[rt][2] * scB, b3 = accB[rt][3] * scB;
      int wb = __builtin_amdgcn_cvt_pk_fp8_f32(b0, b1, 0, false);
      wb = __builtin_amdgcn_cvt_pk_fp8_f32(b2, b3, wb, true);
      *(int*)(VwB + l15 * 520 + 64 * wv + 16 * rt + 4 * g) = wb;
    }
    __syncthreads();
  }

  // final store: bf16 vectors, ledgers, Ssum (dir 0; f32 accumulators)
  unsigned short* base = dir ? Z : U;
  unsigned short* dstA = base + (size_t)chA * 512 + 64 * wv + 4 * g;
  unsigned short* dstB = base + (size_t)chB * 512 + 64 * wv + 4 * g;
#pragma unroll
  for (int rt = 0; rt < 4; ++rt) {
    uint2 oa, ob;
    oa.x = (unsigned)f2bf(accA[rt][0]) | ((unsigned)f2bf(accA[rt][1]) << 16);
    oa.y = (unsigned)f2bf(accA[rt][2]) | ((unsigned)f2bf(accA[rt][3]) << 16);
    ob.x = (unsigned)f2bf(accB[rt][0]) | ((unsigned)f2bf(accB[rt][1]) << 16);
    ob.y = (unsigned)f2bf(accB[rt][2]) | ((unsigned)f2bf(accB[rt][3]) << 16);
    *(uint2*)(dstA + 16 * rt) = oa;
    *(uint2*)(dstB + 16 * rt) = ob;
  }

  if (dir == 0) {
    float sA = 0.f, sB = 0.f;
#pragma unroll
    for (int rt = 0; rt < 4; ++rt)
#pragma unroll
      for (int j = 0; j < 4; ++j) { sA += accA[rt][j]; sB += accB[rt][j]; }
    sA += __shfl_xor(sA, 16, 64); sA += __shfl_xor(sA, 32, 64);
    sB += __shfl_xor(sB, 16, 64); sB += __shfl_xor(sB, 32, 64);
    __syncthreads();                       // cred safe to reuse
    if (lane < 16) {
      cred[wv][lane] = sA;
      cred[wv][16 + lane] = sB;
    }
    __syncthreads();
    if (wv == 0 && lane < 16) {
      float tA = 0.f, tB = 0.f;
#pragma unroll
      for (int q = 0; q < 8; ++q) { tA += cred[q][lane]; tB += cred[q][16 + lane]; }
      Ssum[grp * 32 + lane] = tA;
      Ssum[grp * 32 + 16 + lane] = tB;
      Aled[grp * 32 + lane] = ledA;
      Aled[grp * 32 + 16 + lane] = ledB;
    }
  } else {
    if (wv == 0 && lane < 16) {
      Bled[grp * 32 + lane] = ledA;
      Bled[grp * 32 + 16 + lane] = ledB;
    }
  }
}

// ---------------- combine: parts[cc] = ln(z_cc . u_{cc-1}) + ledgers - ln(s_cc) ----------------
__global__ __launch_bounds__(64) void combine_k(const unsigned short* __restrict__ U,
                                                const unsigned short* __restrict__ Z,
                                                const int* __restrict__ Aled,
                                                const int* __restrict__ Bled,
                                                const float* __restrict__ Ssum,
                                                double* __restrict__ parts) {
  int cc = blockIdx.x + 1;           // 1..CHUNKS-1
  int lane = threadIdx.x;
  float p = 0.f;
  for (int r = lane; r < 512; r += 64)
    p += bf2f(Z[(size_t)cc * 512 + r]) * bf2f(U[(size_t)(cc - 1) * 512 + r]);
#pragma unroll
  for (int off = 1; off < 64; off <<= 1) p += __shfl_xor(p, off, 64);
  if (lane == 0) {
    const double LN2 = 0.69314718055994530942;
    double term = log((double)p) + LN2 * (double)(Aled[cc - 1] + Bled[cc]);
    if (cc <= CHUNKS - 2)
      term -= log((double)Ssum[cc]) + LN2 * (double)Aled[cc];
    parts[cc] = term;
  }
}

// ---------------- final: out = sum(parts) - gold ----------------
__global__ __launch_bounds__(256) void final2_k(const double* __restrict__ parts,
                                                const float* __restrict__ gpart,
                                                float* __restrict__ outp) {
  __shared__ double red[256];
  double s = 0.0;
  for (int i = 1 + (int)threadIdx.x; i < CHUNKS; i += 256) s += parts[i];
  red[threadIdx.x] = s;
  __syncthreads();
  for (int h = 128; h > 0; h >>= 1) {
    if ((int)threadIdx.x < h) red[threadIdx.x] += red[threadIdx.x + h];
    __syncthreads();
  }
  if (threadIdx.x == 0) {
    double g = 0.0;
    for (int q = 0; q < 32; ++q) g += (double)gpart[q];
    outp[0] = (float)(red[0] - g);
  }
}

extern "C" void kernel_launch(void* const* d_in, const int* in_sizes, int n_in,
                              void* d_out, int out_size, void* d_ws, size_t ws_size,
                              hipStream_t stream) {
  const float* obs = (const float*)d_in[0];   // (K, T) f32
  const int* tags = (const int*)d_in[1];      // (T,) i32
  const float* tr = (const float*)d_in[2];    // (K, K) f32
  float* out = (float*)d_out;

  uint8_t* ws = (uint8_t*)d_ws;
  uint8_t* E8 = ws + OFF_E8;
  uint8_t* ET8 = ws + OFF_ET8;
  unsigned short* U = (unsigned short*)(ws + OFF_U);
  unsigned short* Z = (unsigned short*)(ws + OFF_Z);
  float* gpart = (float*)(ws + OFF_GPART);
  int* Aled = (int*)(ws + OFF_ALED);
  int* Bled = (int*)(ws + OFF_BLED);
  float* Ssum = (float*)(ws + OFF_SSUM);
  double* parts = (double*)(ws + OFF_PARTS);
  uint8_t* expT = ws + OFF_EXPT;

  hipLaunchKernelGGL(prep_k, dim3(512), dim3(512), 0, stream, tr, E8, ET8);
  hipLaunchKernelGGL(texp_k, dim3(512 * 8), dim3(256), 0, stream, obs, expT);
  hipLaunchKernelGGL(gold_k, dim3(32), dim3(1024), 0, stream, obs, tags, tr, gpart);
  hipLaunchKernelGGL(uv_k, dim3(NGRP * 2), dim3(512), 0, stream,
                     E8, ET8, expT, U, Z, Aled, Bled, Ssum);
  hipLaunchKernelGGL(combine_k, dim3(CHUNKS - 1), dim3(64), 0, stream,
                     U, Z, Aled, Bled, Ssum, parts);
  hipLaunchKernelGGL(final2_k, dim3(1), dim3(256), 0, stream, parts, gpart, out);
}

// Round 19
// 78.359 us; speedup vs baseline: 1.7288x; 1.0837x over previous
//
#include <hip/hip_runtime.h>
#include <cstdint>
#include <cstddef>

// Problem constants
#define K_ 512
#define T_ 32768
#define CHUNKS 8192
#define LSTEP 4            // T_/CHUNKS
#define COLS 64            // chunk-columns per WG (4 groups of 16)
#define NGRP 128           // CHUNKS/COLS

// workspace layout (bytes) -- total ~24.7 MB
#define OFF_E8    0ul        // 512*512 fp8 row-major
#define OFF_ET8   262144ul   // transposed fp8
#define OFF_U     524288ul   // 8192 x 512 fp8 = 4 MB
#define OFF_Z     4718592ul  // 8192 x 512 fp8 = 4 MB
#define OFF_GPART 8912896ul  // 128 f32
#define OFF_ALED  8913920ul  // 8192 int = 32 KB
#define OFF_BLED  8946688ul  // 8192 int
#define OFF_SSUM  8979456ul  // 8192 f32
#define OFF_PARTS 9012224ul  // 8192 double (end 9077760)
#define OFF_EXPT  9077760ul  // expT[t][k] fp8: 16 MB (end 25854976)

#define FP8MAX 440.f

typedef float f32x4 __attribute__((ext_vector_type(4)));
typedef int i32x8 __attribute__((ext_vector_type(8)));

// 32B LDS fragment via 4x ds_read_b64 (conflict-free at stride 520; validated r4-r18)
static __device__ __forceinline__ i32x8 lds_ld32(const uint8_t* p) {
  long long a = *(const long long*)p;
  long long b = *(const long long*)(p + 8);
  long long c = *(const long long*)(p + 16);
  long long d = *(const long long*)(p + 24);
  i32x8 r;
  r[0] = (int)a; r[1] = (int)(a >> 32);
  r[2] = (int)b; r[3] = (int)(b >> 32);
  r[4] = (int)c; r[5] = (int)(c >> 32);
  r[6] = (int)d; r[7] = (int)(d >> 32);
  return r;
}

// ---------------- setup: texp (blocks 0..4095) | gold (4096..4223) | prep (4224..4735) ----------------
__global__ __launch_bounds__(256) void setup_k(const float* __restrict__ obs,
                                               const int* __restrict__ tags,
                                               const float* __restrict__ tr,
                                               uint8_t* __restrict__ E8,
                                               uint8_t* __restrict__ ET8,
                                               uint8_t* __restrict__ expT,
                                               float* __restrict__ gpart) {
  __shared__ __align__(16) uint8_t smem[64 * 68];
  const int b = blockIdx.x;
  if (b < 4096) {
    // texp: expT[t][k] = fp8(exp(obs[k][t])), 64x64 tile
    uint8_t (*tile)[68] = (uint8_t(*)[68])smem;
    const int t0 = (b & 511) * 64;
    const int k0 = (b >> 9) * 64;
    const int tx = threadIdx.x & 63;
    const int ky = threadIdx.x >> 6;
#pragma unroll
    for (int q = 0; q < 16; ++q) {
      int k = ky * 16 + q;
      float v = obs[(size_t)(k0 + k) * T_ + t0 + tx];
      float e = fminf(__expf(v), FP8MAX);
      int w = __builtin_amdgcn_cvt_pk_fp8_f32(e, e, 0, false);
      tile[tx][k] = (uint8_t)(w & 0xff);
    }
    __syncthreads();
    const int ty = threadIdx.x >> 2;
    const int kq = (threadIdx.x & 3) * 16;
    const uint8_t* src = &tile[ty][kq];
    uint4 o;
    o.x = *(const unsigned*)(src + 0);
    o.y = *(const unsigned*)(src + 4);
    o.z = *(const unsigned*)(src + 8);
    o.w = *(const unsigned*)(src + 12);
    *(uint4*)(expT + (size_t)(t0 + ty) * 512 + k0 + kq) = o;
  } else if (b < 4224) {
    // gold partials: 128 blocks x 256 threads, 1 elem each
    float* red = (float*)smem;
    int i = (b - 4096) * 256 + threadIdx.x;
    float s = 0.f;
    if (i < T_ - 1) {
      int cur = tags[i], nxt = tags[i + 1];
      s = tr[nxt * K_ + cur] + obs[(size_t)nxt * T_ + i];
    }
    red[threadIdx.x] = s;
    __syncthreads();
    for (int h = 128; h > 0; h >>= 1) {
      if ((int)threadIdx.x < h) red[threadIdx.x] += red[threadIdx.x + h];
      __syncthreads();
    }
    if (threadIdx.x == 0) gpart[b - 4096] = red[0];
  } else {
    // prep: E8/ET8 = fp8(exp(tr)); one row per block, 2 elems/thread
    int i = b - 4224;
#pragma unroll
    for (int h = 0; h < 2; ++h) {
      int j = threadIdx.x * 2 + h;
      float e = fminf(__expf(tr[i * 512 + j]), FP8MAX);
      int w = __builtin_amdgcn_cvt_pk_fp8_f32(e, e, 0, false);
      uint8_t bb = (uint8_t)(w & 0xff);
      E8[i * 512 + j] = bb;
      ET8[(size_t)j * 512 + i] = bb;
    }
  }
}

// ---------------- uv: 64 chunk recurrences per WG (4 groups x 16) via MFMA ----------------
// LSTEP=4; deferred per-column pow2 renorm (r8-validated predictor: sigma for step s
// from step s-1's realized per-column max; exact integer ledger; FP8MAX saturation
// guard) -> streaming per-group epilogue (16 acc live, no spill) and ONE barrier per
// step (cred double-buffered, reduce piggybacks on the V barrier). expT factors
// rotate-prefetched one step ahead (hides HBM latency under the MFMA issue).
__global__ __launch_bounds__(512, 2)
void uv_k(const uint8_t* __restrict__ E8, const uint8_t* __restrict__ ET8,
          const uint8_t* __restrict__ expT,
          uint8_t* __restrict__ U, uint8_t* __restrict__ Z,
          int* __restrict__ Aled, int* __restrict__ Bled,
          float* __restrict__ Ssum) {
  __shared__ __align__(16) uint8_t Vb[2][COLS * 520];   // 66560 B
  __shared__ float cred[2][8][COLS];                    // 4096 B (double-buffered)

  const int tid = threadIdx.x;
  const int wv = tid >> 6;
  const int lane = tid & 63;
  const int l15 = lane & 15;
  const int g = lane >> 4;
  const int dir = blockIdx.x & 1;
  const int grp = blockIdx.x >> 1;

  // E (or E^T) fragments: lane holds A[row=64wv+16rt+l15][k=128kt+32g..+31]
  const uint8_t* M = dir ? ET8 : E8;
  i32x8 ef[4][4];
#pragma unroll
  for (int rt = 0; rt < 4; ++rt)
#pragma unroll
    for (int kt = 0; kt < 4; ++kt)
      ef[rt][kt] = *(const i32x8*)(M +
          ((64 * wv + 16 * rt + l15) * 512 + 128 * kt + 32 * g));

  // init V[0]
  if (dir == 0) {
    for (int i = tid; i < COLS * 520 / 4; i += 512)
      ((int*)Vb[0])[i] = 0x38383838;               // fp8 1.0 (pad unused)
  } else {
#pragma unroll 1
    for (int c = 0; c < COLS; ++c)
      Vb[0][c * 520 + tid] =
          expT[(size_t)((grp * COLS + c) * LSTEP + (LSTEP - 1)) * 512 + tid];
  }
  __syncthreads();

  int led[4] = {0, 0, 0, 0};
  int Sprev[4], sigp[4];
  const f32x4 z4 = (f32x4){0.f, 0.f, 0.f, 0.f};

  // expT rotate: load step-0 factors
  unsigned ewc[4][4];
#pragma unroll
  for (int q = 0; q < 4; ++q) {
    int ch = grp * COLS + q * 16 + l15;
    int te = dir ? (ch * LSTEP + LSTEP - 2) : (ch * LSTEP);
    const uint8_t* ep = expT + (size_t)te * 512 + 64 * wv + 4 * g;
#pragma unroll
    for (int rt = 0; rt < 4; ++rt) ewc[q][rt] = *(const unsigned*)(ep + 16 * rt);
  }

#pragma unroll 1
  for (int s = 0; s < LSTEP; ++s) {
    const uint8_t* Vr = Vb[s & 1];
    uint8_t* Vw = Vb[(s & 1) ^ 1];
    const bool doexp = (dir == 0) || (s < LSTEP - 1);
    const bool last = (s == LSTEP - 1);

    // prefetch NEXT step's exp factors (skip when next step has none)
    unsigned ewn[4][4];
    const bool pf = dir ? (s < LSTEP - 2) : (s < LSTEP - 1);
    if (pf) {
#pragma unroll
      for (int q = 0; q < 4; ++q) {
        int ch = grp * COLS + q * 16 + l15;
        int te = dir ? (ch * LSTEP + LSTEP - 3 - s) : (ch * LSTEP + s + 1);
        const uint8_t* ep = expT + (size_t)te * 512 + 64 * wv + 4 * g;
#pragma unroll
        for (int rt = 0; rt < 4; ++rt) ewn[q][rt] = *(const unsigned*)(ep + 16 * rt);
      }
    }

    // ---- deferred per-column sigma (from step s-1's cred; bootstrap at s=0) ----
    int sig[4];
#pragma unroll
    for (int q = 0; q < 4; ++q) {
      if (s == 0) {
        sig[q] = -13;
        sigp[q] = -13;
        Sprev[q] = 0;
      } else {
        const float* cr = &cred[(s & 1) ^ 1][0][q * 16 + l15];
        float m = cr[0];
#pragma unroll
        for (int w2 = 1; w2 < 8; ++w2) m = fmaxf(m, cr[(size_t)w2 * COLS]);
        int S1 = (int)((__float_as_uint(m) >> 23) & 255) - 127;
        S1 = min(max(S1, -60), 60);
        int gam = (s == 1) ? 16 : (S1 - sigp[q]) - Sprev[q];
        gam = min(max(gam, 2), 20);
        int target = last ? 0 : 3;
        int sg = target - S1 - gam;
        sg = min(max(sg, -60), 30);
        Sprev[q] = S1;
        sigp[q] = sg;
        sig[q] = sg;
      }
      led[q] += -sig[q];                  // TRUE = stored * 2^led
    }

    // ---- 4 groups: 16-MFMA chain then streaming epilogue ----
#pragma unroll
    for (int q = 0; q < 4; ++q) {
      const uint8_t* pb = Vr + (16 * q + l15) * 520 + 32 * g;
      f32x4 acc[4];
      {
        i32x8 bfr = lds_ld32(pb);
#pragma unroll
        for (int rt = 0; rt < 4; ++rt)
          acc[rt] = __builtin_amdgcn_mfma_scale_f32_16x16x128_f8f6f4(
              ef[rt][0], bfr, z4, 0, 0, 0, 0x7f7f7f7f, 0, 0x7f7f7f7f);
      }
#pragma unroll
      for (int kt = 1; kt < 4; ++kt) {
        i32x8 bfr = lds_ld32(pb + 128 * kt);
#pragma unroll
        for (int rt = 0; rt < 4; ++rt)
          acc[rt] = __builtin_amdgcn_mfma_scale_f32_16x16x128_f8f6f4(
              ef[rt][kt], bfr, acc[rt], 0, 0, 0, 0x7f7f7f7f, 0, 0x7f7f7f7f);
      }

      const float scf = __uint_as_float((unsigned)(127 + sig[q]) << 23);
      float vmax = 0.f, csum = 0.f;
      int ch = grp * COLS + q * 16 + l15;
      uint8_t* gdst = (dir ? Z : U) + (size_t)ch * 512 + 64 * wv + 4 * g;
#pragma unroll
      for (int rt = 0; rt < 4; ++rt) {
        float v0 = acc[rt][0], v1 = acc[rt][1], v2 = acc[rt][2], v3 = acc[rt][3];
        if (doexp) {
          int w = (int)ewc[q][rt];
          v0 *= __builtin_amdgcn_cvt_f32_fp8(w, 0);
          v1 *= __builtin_amdgcn_cvt_f32_fp8(w, 1);
          v2 *= __builtin_amdgcn_cvt_f32_fp8(w, 2);
          v3 *= __builtin_amdgcn_cvt_f32_fp8(w, 3);
        }
        v0 = fminf(v0 * scf, FP8MAX); v1 = fminf(v1 * scf, FP8MAX);
        v2 = fminf(v2 * scf, FP8MAX); v3 = fminf(v3 * scf, FP8MAX);
        vmax = fmaxf(vmax, fmaxf(fmaxf(v0, v1), fmaxf(v2, v3)));
        int w32 = __builtin_amdgcn_cvt_pk_fp8_f32(v0, v1, 0, false);
        w32 = __builtin_amdgcn_cvt_pk_fp8_f32(v2, v3, w32, true);
        if (!last) {
          *(int*)(Vw + (16 * q + l15) * 520 + 64 * wv + 16 * rt + 4 * g) = w32;
        } else {
          *(int*)(gdst + 16 * rt) = w32;
          csum += (v0 + v1) + (v2 + v3);
        }
      }
      // per-column max partial -> cred[s&1] (read at step s+1)
      vmax = fmaxf(vmax, __shfl_xor(vmax, 16, 64));
      vmax = fmaxf(vmax, __shfl_xor(vmax, 32, 64));
      if (!last) {
        if (lane < 16) cred[s & 1][wv][q * 16 + lane] = vmax;
      } else if (dir == 0) {
        csum += __shfl_xor(csum, 16, 64);
        csum += __shfl_xor(csum, 32, 64);
        if (lane < 16) cred[s & 1][wv][q * 16 + lane] = csum;   // reuse for Ssum
      }
      // rotate exp factors for next step
      if (pf) {
#pragma unroll
        for (int rt = 0; rt < 4; ++rt) ewc[q][rt] = ewn[q][rt];
      }
    }
    __syncthreads();
  }

  // ledgers + Ssum (cred[(LSTEP-1)&1] holds dir0 column sums after final barrier)
  if (wv == 0 && lane < 16) {
#pragma unroll
    for (int q = 0; q < 4; ++q) {
      int ch = grp * COLS + q * 16 + lane;
      if (dir == 0) {
        float t = 0.f;
#pragma unroll
        for (int w2 = 0; w2 < 8; ++w2) t += cred[(LSTEP - 1) & 1][w2][q * 16 + lane];
        Ssum[ch] = t;
        Aled[ch] = led[q];
      } else {
        Bled[ch] = led[q];
      }
    }
  }
}

// ---------------- combine: parts[cc] = ln(z_cc . u_{cc-1}) + ledgers - ln(s_cc) ----------------
__global__ __launch_bounds__(64) void combine_k(const uint8_t* __restrict__ U,
                                                const uint8_t* __restrict__ Z,
                                                const int* __restrict__ Aled,
                                                const int* __restrict__ Bled,
                                                const float* __restrict__ Ssum,
                                                double* __restrict__ parts) {
  int cc = blockIdx.x + 1;           // 1..CHUNKS-1
  int lane = threadIdx.x;
  const unsigned* zp = (const unsigned*)(Z + (size_t)cc * 512);
  const unsigned* up = (const unsigned*)(U + (size_t)(cc - 1) * 512);
  float p = 0.f;
#pragma unroll
  for (int it = 0; it < 2; ++it) {
    unsigned zw = zp[lane + 64 * it];
    unsigned uw = up[lane + 64 * it];
    p += __builtin_amdgcn_cvt_f32_fp8((int)zw, 0) * __builtin_amdgcn_cvt_f32_fp8((int)uw, 0);
    p += __builtin_amdgcn_cvt_f32_fp8((int)zw, 1) * __builtin_amdgcn_cvt_f32_fp8((int)uw, 1);
    p += __builtin_amdgcn_cvt_f32_fp8((int)zw, 2) * __builtin_amdgcn_cvt_f32_fp8((int)uw, 2);
    p += __builtin_amdgcn_cvt_f32_fp8((int)zw, 3) * __builtin_amdgcn_cvt_f32_fp8((int)uw, 3);
  }
#pragma unroll
  for (int off = 1; off < 64; off <<= 1) p += __shfl_xor(p, off, 64);
  if (lane == 0) {
    const double LN2 = 0.69314718055994530942;
    double term = log((double)p) + LN2 * (double)(Aled[cc - 1] + Bled[cc]);
    if (cc <= CHUNKS - 2)
      term -= log((double)Ssum[cc]) + LN2 * (double)Aled[cc];
    parts[cc] = term;
  }
}

// ---------------- final: out = sum(parts) - gold ----------------
__global__ __launch_bounds__(256) void final2_k(const double* __restrict__ parts,
                                                const float* __restrict__ gpart,
                                                float* __restrict__ outp) {
  __shared__ double red[256];
  double s = 0.0;
  for (int i = 1 + (int)threadIdx.x; i < CHUNKS; i += 256) s += parts[i];
  red[threadIdx.x] = s;
  __syncthreads();
  for (int h = 128; h > 0; h >>= 1) {
    if ((int)threadIdx.x < h) red[threadIdx.x] += red[threadIdx.x + h];
    __syncthreads();
  }
  if (threadIdx.x == 0) {
    double g = 0.0;
    for (int q = 0; q < 128; ++q) g += (double)gpart[q];
    outp[0] = (float)(red[0] - g);
  }
}

extern "C" void kernel_launch(void* const* d_in, const int* in_sizes, int n_in,
                              void* d_out, int out_size, void* d_ws, size_t ws_size,
                              hipStream_t stream) {
  const float* obs = (const float*)d_in[0];   // (K, T) f32
  const int* tags = (const int*)d_in[1];      // (T,) i32
  const float* tr = (const float*)d_in[2];    // (K, K) f32
  float* out = (float*)d_out;

  uint8_t* ws = (uint8_t*)d_ws;
  uint8_t* E8 = ws + OFF_E8;
  uint8_t* ET8 = ws + OFF_ET8;
  uint8_t* U = ws + OFF_U;
  uint8_t* Z = ws + OFF_Z;
  float* gpart = (float*)(ws + OFF_GPART);
  int* Aled = (int*)(ws + OFF_ALED);
  int* Bled = (int*)(ws + OFF_BLED);
  float* Ssum = (float*)(ws + OFF_SSUM);
  double* parts = (double*)(ws + OFF_PARTS);
  uint8_t* expT = ws + OFF_EXPT;

  hipLaunchKernelGGL(setup_k, dim3(4736), dim3(256), 0, stream,
                     obs, tags, tr, E8, ET8, expT, gpart);
  hipLaunchKernelGGL(uv_k, dim3(NGRP * 2), dim3(512), 0, stream,
                     E8, ET8, expT, U, Z, Aled, Bled, Ssum);
  hipLaunchKernelGGL(combine_k, dim3(CHUNKS - 1), dim3(64), 0, stream,
                     U, Z, Aled, Bled, Ssum, parts);
  hipLaunchKernelGGL(final2_k, dim3(1), dim3(256), 0, stream, parts, gpart, out);
}